// Round 6
// baseline (111.508 us; speedup 1.0000x reference)
//
#include <hip/hip_runtime.h>
#include <hip/hip_bf16.h>
#include <stdint.h>

typedef __attribute__((ext_vector_type(8)))  short  s16x8;
typedef __attribute__((ext_vector_type(8)))  __bf16 bf16x8;
typedef __attribute__((ext_vector_type(16))) float  f32x16;

#define N_ROWS  32768   // 64 * 512
#define N_CODES 1024
#define DIM     512
#define BK      64      // K-tile: 128B LDS rows -> 8-slot XOR is conflict-free (R2: measured 0)

static __device__ __forceinline__ short f2bf(float f) {
    unsigned u = __float_as_uint(f);
    u += 0x7fffu + ((u >> 16) & 1u);   // round-to-nearest-even
    return (short)(u >> 16);
}
static __device__ __forceinline__ float bf2f(short h) {
    return __uint_as_float(((unsigned)(unsigned short)h) << 16);
}

typedef const __attribute__((address_space(1))) uint32_t guint;
typedef __attribute__((address_space(3))) uint32_t luint;
static __device__ __forceinline__ void gl_lds16(const short* g, short* l) {
    __builtin_amdgcn_global_load_lds((guint*)g, (luint*)l, 16, 0, 0);
}

// ---------------- K0a: convert X to bf16 ----------------
__global__ void __launch_bounds__(256)
convertX(const float* __restrict__ X, short* __restrict__ Xb) {
    const size_t i = ((size_t)blockIdx.x * 256 + threadIdx.x) * 8;
    float4 a = *(const float4*)(X + i);
    float4 b = *(const float4*)(X + i + 4);
    s16x8 v = { f2bf(a.x), f2bf(a.y), f2bf(a.z), f2bf(a.w),
                f2bf(b.x), f2bf(b.y), f2bf(b.z), f2bf(b.w) };
    *(s16x8*)(Xb + i) = v;
}

// ---------------- K0b: convert W to bf16 + codebook norms ----------------
__global__ void __launch_bounds__(256)
convertW(const float* __restrict__ W, short* __restrict__ Wb,
         float* __restrict__ wnorm) {
    const int lane = threadIdx.x & 63;
    const int code = blockIdx.x * 4 + (threadIdx.x >> 6);
    const float4* wp = (const float4*)(W + (size_t)code * DIM + lane * 8);
    float4 a = wp[0], b = wp[1];
    s16x8 v = { f2bf(a.x), f2bf(a.y), f2bf(a.z), f2bf(a.w),
                f2bf(b.x), f2bf(b.y), f2bf(b.z), f2bf(b.w) };
    *(s16x8*)(Wb + (size_t)code * DIM + lane * 8) = v;
    float s = a.x*a.x + a.y*a.y + a.z*a.z + a.w*a.w
            + b.x*b.x + b.y*b.y + b.z*b.z + b.w*b.w;
    #pragma unroll
    for (int d = 1; d < 64; d <<= 1) s += __shfl_xor(s, d);
    if (lane == 0) wnorm[code] = s;
}

// ---------------- K2: bf16 MFMA GEMM (32x32x16) + per-tile argmin ----------------
// 128x128 tile, BK=64, single 32KB LDS, 4 waves (2x2), wave = 64x64 =
// 2x2 MFMA tiles of 32x32. 128B rows + 8-slot XOR swizzle p = q ^ (row&7),
// applied both-sides: pre-swizzled global source (linear gl_lds dest) +
// swizzled ds_read. R2 measured this layout at 0 bank conflicts.
// XCD row-chunk swizzle (R5-verified): XCD x owns a 4MB X row-slice in its
// L2 and sweeps the 8 col-blocks within each 128-row window.
__global__ void __launch_bounds__(256)
gemm_argmin(const short* __restrict__ Xb, const short* __restrict__ Wb,
            const float* __restrict__ wnorm, float2* __restrict__ pairs) {
    __shared__ __align__(16) short As[128 * BK];
    __shared__ __align__(16) short Bs[128 * BK];

    const int tid  = threadIdx.x;
    const int lane = tid & 63;
    const int wave = tid >> 6;
    const int wr = wave >> 1, wc = wave & 1;
    const int l31 = lane & 31, lh = lane >> 5;

    // bid = x + 8*(c + 8*rl): xcd x, colBlk c, local rowBlk rl
    const int bid = blockIdx.x;
    const int colBase = ((bid >> 3) & 7) * 128;
    const int rowBase = ((bid & 7) * 32 + (bid >> 6)) * 128;

    // staging: thread -> rows (tid>>3) + j*32, phys slot (tid&7);
    // source slot pre-swizzled by row&7 = (tid>>3)&7. LDS dest linear.
    const int ssw = ((tid & 7) ^ ((tid >> 3) & 7)) * 8;
    const short* aS = Xb + (size_t)(rowBase + (tid >> 3)) * DIM + ssw;
    const short* bS = Wb + (size_t)(colBase + (tid >> 3)) * DIM + ssw;
    short* aD = &As[tid * 8];
    short* bD = &Bs[tid * 8];

    f32x16 acc00 = (f32x16)0.f, acc01 = (f32x16)0.f;
    f32x16 acc10 = (f32x16)0.f, acc11 = (f32x16)0.f;

    const int fsw = l31 & 7;                 // read-side slot XOR
    const int ar0 = (wr*64      + l31) * BK;
    const int ar1 = (wr*64 + 32 + l31) * BK;
    const int br0 = (wc*64      + l31) * BK;
    const int br1 = (wc*64 + 32 + l31) * BK;

    for (int t = 0; t < DIM / BK; ++t) {
        #pragma unroll
        for (int j = 0; j < 4; ++j) {
            gl_lds16(aS + (size_t)(j * 32) * DIM + t * BK, aD + j * 2048);
            gl_lds16(bS + (size_t)(j * 32) * DIM + t * BK, bD + j * 2048);
        }
        __syncthreads();

        #pragma unroll
        for (int ks = 0; ks < 4; ++ks) {
            const int qo = ((ks * 2 + lh) ^ fsw) * 8;   // swizzled slot (shorts)
            bf16x8 a0 = __builtin_bit_cast(bf16x8, *(const s16x8*)&As[ar0 + qo]);
            bf16x8 a1 = __builtin_bit_cast(bf16x8, *(const s16x8*)&As[ar1 + qo]);
            bf16x8 b0 = __builtin_bit_cast(bf16x8, *(const s16x8*)&Bs[br0 + qo]);
            bf16x8 b1 = __builtin_bit_cast(bf16x8, *(const s16x8*)&Bs[br1 + qo]);
            acc00 = __builtin_amdgcn_mfma_f32_32x32x16_bf16(a0, b0, acc00, 0, 0, 0);
            acc01 = __builtin_amdgcn_mfma_f32_32x32x16_bf16(a0, b1, acc01, 0, 0, 0);
            acc10 = __builtin_amdgcn_mfma_f32_32x32x16_bf16(a1, b0, acc10, 0, 0, 0);
            acc11 = __builtin_amdgcn_mfma_f32_32x32x16_bf16(a1, b1, acc11, 0, 0, 0);
        }
        __syncthreads();
    }

    // Epilogue: score = wnorm[col] - 2*dot. C/D: col = lane&31,
    // row = mi*32 + 4*lh + (reg&3) + 8*(reg>>2). Reduce over 32 lanes.
    float wnv[2]; int wcolv[2];
    #pragma unroll
    for (int ni = 0; ni < 2; ++ni) {
        wcolv[ni] = colBase + wc*64 + ni*32 + l31;
        wnv[ni] = wnorm[wcolv[ni]];
    }
    const int chunk = (colBase >> 6) + wc;   // 0..15

#define ARGMIN_TILE(mi, A0, A1) do {                                          \
    _Pragma("unroll")                                                         \
    for (int reg = 0; reg < 16; ++reg) {                                      \
        float bv = wnv[0] - 2.0f * (A0)[reg];                                 \
        int   bi = wcolv[0];                                                  \
        float sc = wnv[1] - 2.0f * (A1)[reg];                                 \
        if (sc < bv || (sc == bv && wcolv[1] < bi)) { bv = sc; bi = wcolv[1]; } \
        _Pragma("unroll")                                                     \
        for (int d = 1; d < 32; d <<= 1) {                                    \
            float ov = __shfl_xor(bv, d);                                     \
            int   oi = __shfl_xor(bi, d);                                     \
            if (ov < bv || (ov == bv && oi < bi)) { bv = ov; bi = oi; }       \
        }                                                                     \
        if (l31 == 0) {                                                       \
            const int row = rowBase + wr*64 + (mi)*32 + 4*lh                  \
                          + (reg & 3) + 8*(reg >> 2);                         \
            pairs[(size_t)row * 16 + chunk] = make_float2(bv, __int_as_float(bi)); \
        }                                                                     \
    } } while (0)

    ARGMIN_TILE(0, acc00, acc01);
    ARGMIN_TILE(1, acc10, acc11);
#undef ARGMIN_TILE
}

// ---------------- K3: combine 16 chunk-minima, bf16 row loss (f32 accum) ----------------
__global__ void __launch_bounds__(256)
combine_loss(const short* __restrict__ Xb, const short* __restrict__ Wb,
             const float2* __restrict__ pairs, float* __restrict__ partial) {
    __shared__ float psum[4];
    const int lane = threadIdx.x & 63;
    const int wv   = threadIdx.x >> 6;
    const int row  = blockIdx.x * 4 + wv;
    float bv; int bi;
    if (lane < 16) {
        float2 p = pairs[(size_t)row * 16 + lane];
        bv = p.x; bi = __float_as_int(p.y);
    } else {
        bv = __int_as_float(0x7f800000);  // +inf
        bi = 0x7fffffff;
    }
    #pragma unroll
    for (int d = 1; d < 64; d <<= 1) {
        float ov = __shfl_xor(bv, d);
        int   oi = __shfl_xor(bi, d);
        if (ov < bv || (ov == bv && oi < bi)) { bv = ov; bi = oi; }
    }
    s16x8 xv = *(const s16x8*)(Xb + (size_t)row * DIM + lane * 8);
    s16x8 wvv = *(const s16x8*)(Wb + (size_t)bi * DIM + lane * 8);
    float s = 0.f;
    #pragma unroll
    for (int j = 0; j < 8; ++j) {
        float dx = bf2f(xv[j]) - bf2f(wvv[j]);
        s += dx * dx;
    }
    #pragma unroll
    for (int d = 1; d < 64; d <<= 1) s += __shfl_xor(s, d);
    if (lane == 0) psum[wv] = s;
    __syncthreads();
    if (threadIdx.x == 0)
        partial[blockIdx.x] = psum[0] + psum[1] + psum[2] + psum[3];
}

// ---------------- K4: final mean over 8192 partials (double accum) ----------------
__global__ void __launch_bounds__(256)
finalize(const float* __restrict__ partial, float* __restrict__ out) {
    __shared__ double sm[256];
    const float4* p = (const float4*)partial;   // 2048 float4s
    double s = 0.0;
    #pragma unroll
    for (int i = 0; i < 8; ++i) {
        float4 v = p[threadIdx.x + i * 256];
        s += (double)v.x + (double)v.y + (double)v.z + (double)v.w;
    }
    sm[threadIdx.x] = s;
    __syncthreads();
    for (int st = 128; st > 0; st >>= 1) {
        if (threadIdx.x < st) sm[threadIdx.x] += sm[threadIdx.x + st];
        __syncthreads();
    }
    if (threadIdx.x == 0)
        out[0] = (float)(sm[0] / (double)((size_t)N_ROWS * DIM));
}

extern "C" void kernel_launch(void* const* d_in, const int* in_sizes, int n_in,
                              void* d_out, int out_size, void* d_ws, size_t ws_size,
                              hipStream_t stream) {
    const float* X = (const float*)d_in[0];   // [32768][512]
    const float* W = (const float*)d_in[1];   // [1024][512]
    char* ws = (char*)d_ws;
    short*  Xb      = (short*)ws;                          // 32 MB @ 0
    short*  Wb      = (short*)(ws + 33554432);             // 1 MB
    float*  wnorm   = (float*)(ws + 34603008);             // 4 KB
    float2* pairs   = (float2*)(ws + 34607104);            // 4 MB
    float*  partial = (float*)(ws + 38801408);             // 32 KB
    float*  out     = (float*)d_out;

    convertX<<<N_ROWS * DIM / (256 * 8), 256, 0, stream>>>(X, Xb);
    convertW<<<N_CODES / 4, 256, 0, stream>>>(W, Wb, wnorm);
    gemm_argmin<<<2048, 256, 0, stream>>>(Xb, Wb, wnorm, pairs);
    combine_loss<<<N_ROWS / 4, 256, 0, stream>>>(Xb, Wb, pairs, partial);
    finalize<<<1, 256, 0, stream>>>(partial, out);
}

// Round 7
// 70.158 us; speedup vs baseline: 1.5894x; 1.5894x over previous
//
#include <hip/hip_runtime.h>
#include <hip/hip_bf16.h>
#include <stdint.h>

typedef __attribute__((ext_vector_type(8))) short  s16x8;
typedef __attribute__((ext_vector_type(8))) __bf16 bf16x8;
typedef __attribute__((ext_vector_type(4))) float  f32x4;

#define N_ROWS  32768   // 64 * 512
#define N_CODES 1024
#define DIM     512
#define BK      32      // K-tile (shorts)

static __device__ __forceinline__ short f2bf(float f) {
    unsigned u = __float_as_uint(f);
    u += 0x7fffu + ((u >> 16) & 1u);   // round-to-nearest-even
    return (short)(u >> 16);
}

typedef const __attribute__((address_space(1))) uint32_t guint;
typedef __attribute__((address_space(3))) uint32_t luint;
static __device__ __forceinline__ void gl_lds16(const short* g, short* l) {
    __builtin_amdgcn_global_load_lds((guint*)g, (luint*)l, 16, 0, 0);
}

// ---------------- K0a: convert X to bf16 + row norms ----------------
__global__ void __launch_bounds__(256)
convertX(const float* __restrict__ X, short* __restrict__ Xb,
         float* __restrict__ xnorm) {
    const int lane = threadIdx.x & 63;
    const int row  = blockIdx.x * 4 + (threadIdx.x >> 6);
    const float4* xp = (const float4*)(X + (size_t)row * DIM + lane * 8);
    float4 a = xp[0], b = xp[1];
    s16x8 v = { f2bf(a.x), f2bf(a.y), f2bf(a.z), f2bf(a.w),
                f2bf(b.x), f2bf(b.y), f2bf(b.z), f2bf(b.w) };
    *(s16x8*)(Xb + (size_t)row * DIM + lane * 8) = v;
    float s = a.x*a.x + a.y*a.y + a.z*a.z + a.w*a.w
            + b.x*b.x + b.y*b.y + b.z*b.z + b.w*b.w;
    #pragma unroll
    for (int d = 1; d < 64; d <<= 1) s += __shfl_xor(s, d);
    if (lane == 0) xnorm[row] = s;
}

// ---------------- K0b: convert W to bf16 + codebook norms ----------------
__global__ void __launch_bounds__(256)
convertW(const float* __restrict__ W, short* __restrict__ Wb,
         float* __restrict__ wnorm) {
    const int lane = threadIdx.x & 63;
    const int code = blockIdx.x * 4 + (threadIdx.x >> 6);
    const float4* wp = (const float4*)(W + (size_t)code * DIM + lane * 8);
    float4 a = wp[0], b = wp[1];
    s16x8 v = { f2bf(a.x), f2bf(a.y), f2bf(a.z), f2bf(a.w),
                f2bf(b.x), f2bf(b.y), f2bf(b.z), f2bf(b.w) };
    *(s16x8*)(Wb + (size_t)code * DIM + lane * 8) = v;
    float s = a.x*a.x + a.y*a.y + a.z*a.z + a.w*a.w
            + b.x*b.x + b.y*b.y + b.z*b.z + b.w*b.w;
    #pragma unroll
    for (int d = 1; d < 64; d <<= 1) s += __shfl_xor(s, d);
    if (lane == 0) wnorm[code] = s;
}

// ---------------- K2: bf16 MFMA GEMM (16x16x32) + per-tile argmin ----------------
// 128x128 tile, BK=32, DOUBLE-buffered 2x16KB LDS, 4 waves (2x2), wave=64x64.
// R2-verified 0-conflict layout: frag read spans 16 rows/instr (lr=lane&15),
// k-group kg=lane>>4 in slot bits, slot XOR phys = kg ^ ((row>>1)&3), applied
// both-sides (pre-swizzled global source, linear gl_lds dest, swizzled read).
// One __syncthreads per K-step; stage of t+1 issued BEFORE reads of t, so the
// end-of-iter vmcnt drain hides HBM/L2 latency under ~300cy of reads+MFMA.
// XCD row-chunk swizzle (R5-verified, FETCH 20MB): bid = x + 8c + 64rl.
__global__ void __launch_bounds__(256)
gemm_argmin(const short* __restrict__ Xb, const short* __restrict__ Wb,
            const float* __restrict__ wnorm, uint32_t* __restrict__ keys) {
    __shared__ __align__(16) short As[2][128 * BK];
    __shared__ __align__(16) short Bs[2][128 * BK];

    const int tid  = threadIdx.x;
    const int lane = tid & 63;
    const int wave = tid >> 6;
    const int wr = wave >> 1, wc = wave & 1;
    const int lr = lane & 15, kg = lane >> 4;

    const int bid = blockIdx.x;
    const int colBase = ((bid >> 3) & 7) * 128;
    const int rowBase = ((bid & 7) * 32 + (bid >> 6)) * 128;

    // staging: thread -> rows (tid>>2) and (tid>>2)+64, phys slot (tid&3);
    // source k-slot pre-swizzled by (row>>1)&3 = (tid>>3)&3. LDS dest linear.
    const int ssw = ((tid & 3) ^ ((tid >> 3) & 3)) * 8;
    const short* aS = Xb + (size_t)(rowBase + (tid >> 2)) * DIM + ssw;
    const short* bS = Wb + (size_t)(colBase + (tid >> 2)) * DIM + ssw;

#define STAGE(buf, t) do {                                                    \
    gl_lds16(aS + (t) * BK,            &As[buf][tid * 8]);                    \
    gl_lds16(aS + 64*DIM + (t) * BK,   &As[buf][tid * 8 + 2048]);             \
    gl_lds16(bS + (t) * BK,            &Bs[buf][tid * 8]);                    \
    gl_lds16(bS + 64*DIM + (t) * BK,   &Bs[buf][tid * 8 + 2048]);             \
  } while (0)

    f32x4 acc[4][4];
    #pragma unroll
    for (int m = 0; m < 4; ++m)
        #pragma unroll
        for (int n = 0; n < 4; ++n) acc[m][n] = (f32x4)0.f;

    const int fq = (kg ^ ((lr >> 1) & 3)) * 8;   // swizzled read slot (shorts)

    STAGE(0, 0);
    __syncthreads();

    for (int t = 0; t < DIM / BK; ++t) {
        const int cur = t & 1;
        if (t < DIM / BK - 1) STAGE(cur ^ 1, t + 1);   // issue BEFORE reads
        bf16x8 aF[4], bF[4];
        #pragma unroll
        for (int m = 0; m < 4; ++m)
            aF[m] = __builtin_bit_cast(bf16x8,
                *(const s16x8*)&As[cur][(wr*64 + m*16 + lr) * BK + fq]);
        #pragma unroll
        for (int n = 0; n < 4; ++n)
            bF[n] = __builtin_bit_cast(bf16x8,
                *(const s16x8*)&Bs[cur][(wc*64 + n*16 + lr) * BK + fq]);
        #pragma unroll
        for (int m = 0; m < 4; ++m)
            #pragma unroll
            for (int n = 0; n < 4; ++n)
                acc[m][n] = __builtin_amdgcn_mfma_f32_16x16x32_bf16(
                    aF[m], bF[n], acc[m][n], 0, 0, 0);
        __syncthreads();   // drains vmcnt too -> next buffer ready
    }
#undef STAGE

    // Epilogue: score = wnorm[col] - 2*dot, packed into sortable u32 with
    // col in the low 10 bits (tie-break = lowest col, like argmin).
    float wn[4]; int wcol[4];
    #pragma unroll
    for (int n = 0; n < 4; ++n) {
        wcol[n] = colBase + wc*64 + n*16 + lr;
        wn[n] = wnorm[wcol[n]];
    }
    const int chunk = (colBase >> 6) + wc;   // 0..15
    #pragma unroll
    for (int m = 0; m < 4; ++m) {
        #pragma unroll
        for (int r = 0; r < 4; ++r) {
            uint32_t best = 0xFFFFFFFFu;
            #pragma unroll
            for (int n = 0; n < 4; ++n) {
                float sc = wn[n] - 2.0f * acc[m][n][r];
                uint32_t u = __float_as_uint(sc);
                u = (u & 0x80000000u) ? ~u : (u | 0x80000000u);  // sortable
                uint32_t key = (u & ~1023u) | (uint32_t)wcol[n];
                best = min(best, key);
            }
            #pragma unroll
            for (int d = 1; d < 16; d <<= 1)
                best = min(best, (uint32_t)__shfl_xor((int)best, d));
            if (lr == 0) {
                const int row = rowBase + wr*64 + m*16 + kg*4 + r;
                keys[(size_t)row * 16 + chunk] = best;
            }
        }
    }
}

// ---------------- K3: min over 16 chunk keys + xnorm -> block partial ----------------
__global__ void __launch_bounds__(256)
reduce_loss(const uint32_t* __restrict__ keys, const float* __restrict__ xnorm,
            float* __restrict__ partial) {
    __shared__ float sm[256];
    const int row = blockIdx.x * 256 + threadIdx.x;
    const uint4* kp = (const uint4*)(keys + (size_t)row * 16);
    uint4 k0 = kp[0], k1 = kp[1], k2 = kp[2], k3 = kp[3];
    uint32_t mk = min(min(min(k0.x, k0.y), min(k0.z, k0.w)),
                      min(min(k1.x, k1.y), min(k1.z, k1.w)));
    mk = min(mk, min(min(min(k2.x, k2.y), min(k2.z, k2.w)),
                     min(min(k3.x, k3.y), min(k3.z, k3.w))));
    // unpack approx score (low 10 bits were col; truncation bias <= 0.0625)
    uint32_t sb = mk & ~1023u;
    float sc = (sb & 0x80000000u) ? __uint_as_float(sb ^ 0x80000000u)
                                  : __uint_as_float(~sb);
    sm[threadIdx.x] = xnorm[row] + sc;   // ||x||^2 + (||w||^2 - 2 x.w)
    __syncthreads();
    for (int st = 128; st > 0; st >>= 1) {
        if (threadIdx.x < st) sm[threadIdx.x] += sm[threadIdx.x + st];
        __syncthreads();
    }
    if (threadIdx.x == 0) partial[blockIdx.x] = sm[0];
}

// ---------------- K4: final mean over 128 partials (double accum) ----------------
__global__ void __launch_bounds__(128)
finalize(const float* __restrict__ partial, float* __restrict__ out) {
    __shared__ double sm[128];
    sm[threadIdx.x] = (double)partial[threadIdx.x];
    __syncthreads();
    for (int st = 64; st > 0; st >>= 1) {
        if (threadIdx.x < st) sm[threadIdx.x] += sm[threadIdx.x + st];
        __syncthreads();
    }
    if (threadIdx.x == 0)
        out[0] = (float)(sm[0] / (double)((size_t)N_ROWS * DIM));
}

extern "C" void kernel_launch(void* const* d_in, const int* in_sizes, int n_in,
                              void* d_out, int out_size, void* d_ws, size_t ws_size,
                              hipStream_t stream) {
    const float* X = (const float*)d_in[0];   // [32768][512]
    const float* W = (const float*)d_in[1];   // [1024][512]
    char* ws = (char*)d_ws;
    short*    Xb      = (short*)ws;                          // 32 MB @ 0
    short*    Wb      = (short*)(ws + 33554432);             // 1 MB
    float*    wnorm   = (float*)(ws + 34603008);             // 4 KB
    float*    xnorm   = (float*)(ws + 34607104);             // 128 KB
    uint32_t* keys    = (uint32_t*)(ws + 34738176);          // 2 MB
    float*    partial = (float*)(ws + 36835328);             // 512 B
    float*    out     = (float*)d_out;

    convertX<<<N_ROWS / 4, 256, 0, stream>>>(X, Xb, xnorm);
    convertW<<<N_CODES / 4, 256, 0, stream>>>(W, Wb, wnorm);
    gemm_argmin<<<2048, 256, 0, stream>>>(Xb, Wb, wnorm, keys);
    reduce_loss<<<N_ROWS / 256, 256, 0, stream>>>(keys, xnorm, partial);
    finalize<<<1, 128, 0, stream>>>(partial, out);
}